// Round 5
// baseline (558.081 us; speedup 1.0000x reference)
//
#include <hip/hip_runtime.h>

#define EPS 1e-6f

constexpr int N_ = 8;
constexpr int H_ = 720;
constexpr int W_ = 1280;
constexpr int HW = H_ * W_;
constexpr int NPIX = N_ * HW;        // 7,372,800

// Tiling for the privatized splat
constexpr int TH = 40;               // tile rows   (720 = 18*40, exact)
constexpr int TW = 40;               // tile cols   (1280 = 32*40, exact)
constexpr int R_ = 24;               // halo = 3 sigma of the sigma=8 flow
constexpr int LH = TH + 2 * R_;      // 88
constexpr int LW = TW + 2 * R_;      // 88
constexpr int LSZ = LH * LW;         // 7744 positions
constexpr int TILES_H = H_ / TH;     // 18
constexpr int TILES_W = W_ / TW;     // 32
constexpr int TILES_PER_IMG = TILES_H * TILES_W;        // 576
constexpr size_t WS_PER_IMG = (size_t)TILES_PER_IMG * LSZ * 2 * sizeof(float); // ~34 MiB

// clang native vector type — required by __builtin_nontemporal_load
// (HIP's float2 is a class and is rejected by the builtin).
typedef float vfloat2 __attribute__((ext_vector_type(2)));

// Native HW fp atomics (ds_add_f32 / global_atomic_add_f32). Plain
// atomicAdd(float*) lowers to a CAS retry loop without -munsafe-fp-atomics,
// which is a dependent ~250-cycle round-trip per op — the round-3 stall.
__device__ __forceinline__ void fadd_native(float* p, float v) {
    unsafeAtomicAdd(p, v);
}

// ---------------------------------------------------------------------------
// Phase A: per-tile privatized splat for images [n0, n0+ni). One block = one
// 40x40 source tile, 512 threads. Loads for all of a thread's 3-4 pixels are
// hoisted into registers first (latency decoupling), then splat into the
// 88x88 halo'd LDS accumulator with native ds_add_f32. Out-of-halo splats
// (~0.5%) go to d_out via native global atomics. LDS is dumped to a private
// chunk-local ws region with plain coalesced float4 stores.
// ---------------------------------------------------------------------------
__global__ __launch_bounds__(512) void splat_tiled_kernel(
        const float* __restrict__ img,
        const float* __restrict__ counts,
        const float* __restrict__ flo,
        float* __restrict__ ws,          // ni * 576 * LSZ * 2 floats
        float* __restrict__ fb_img,      // fallback accumulators = d_out planes
        float* __restrict__ fb_one,
        int n0) {
    __shared__ float4 lds4[LSZ / 2];     // 7744*2 floats = 61952 B
    float* lds = (float*)lds4;

    int bt = blockIdx.x;                 // chunk-local tile id
    int tc = bt % TILES_W;
    int t2 = bt / TILES_W;
    int tr = t2 % TILES_H;
    int n  = n0 + t2 / TILES_H;
    int row0 = tr * TH;
    int col0 = tc * TW;
    int tid = threadIdx.x;

    // zero LDS
    for (int i = tid; i < LSZ / 2; i += 512)
        lds4[i] = make_float4(0.f, 0.f, 0.f, 0.f);
    __syncthreads();

    int nbase = n * HW;
    int fbase_n = n * 2 * HW;

    // ---- load phase: up to 4 pixels per thread, all loads in flight ----
    float iv[4], cv[4], xx[4], yy[4];
    #pragma unroll
    for (int k = 0; k < 4; ++k) {
        int p = tid + k * 512;
        if (p < TH * TW) {
            int r = p / TW;
            int c = p % TW;
            int h = row0 + r;
            int w = col0 + c;
            int idx = nbase + h * W_ + w;
            iv[k] = img[idx];
            cv[k] = counts[idx];
            int fo = fbase_n + h * W_ + w;
            yy[k] = flo[fo];               // channel 0 shifts W axis
            xx[k] = flo[fo + HW];          // channel 1 shifts H axis
        }
    }

    // ---- splat phase ----
    #pragma unroll
    for (int k = 0; k < 4; ++k) {
        int p = tid + k * 512;
        if (p >= TH * TW) continue;
        int r = p / TW;
        int c = p % TW;
        int h = row0 + r;
        int w = col0 + c;

        float x = xx[k], y = yy[k];
        float x1 = floorf(x);
        float y1 = floorf(y);
        float fx = x - x1;
        float fy = y - y1;
        float gx = 1.0f - fx;
        float gy = 1.0f - fy;
        float ex1 = __expf(-fx * fx);
        float ex2 = __expf(-gx * gx);
        float ey1 = __expf(-fy * fy);
        float ey2 = __expf(-gy * gy);

        float s = (ex1 + ex2) * (ey1 + ey2);
        float inv = cv[k] / s;
        float ivk = iv[k];

        int ix1 = (int)x1 + h;
        int iy1 = (int)y1 + w;

        int ixr[2] = {ix1, ix1 + 1};
        int iyc[2] = {iy1, iy1 + 1};
        float wx[2] = {ex1, ex2};
        float wy[2] = {ey1, ey2};

        #pragma unroll
        for (int a = 0; a < 2; ++a) {
            #pragma unroll
            for (int b = 0; b < 2; ++b) {
                float wwv = wx[a] * wy[b] * inv;
                float wiv = ivk * wwv;
                int lh = ixr[a] - row0 + R_;
                int lw = iyc[b] - col0 + R_;
                if ((unsigned)lh < (unsigned)LH && (unsigned)lw < (unsigned)LW) {
                    int o = (lh * LW + lw) * 2;
                    fadd_native(lds + o,     wiv);   // ds_add_f32
                    fadd_native(lds + o + 1, wwv);
                } else if ((unsigned)ixr[a] < (unsigned)H_ &&
                           (unsigned)iyc[b] < (unsigned)W_) {
                    int o = nbase + ixr[a] * W_ + iyc[b];
                    fadd_native(fb_img + o, wiv);    // rare: out-of-halo tail
                    fadd_native(fb_one + o, wwv);
                }
            }
        }
    }
    __syncthreads();

    // private, coalesced dump: no atomics
    float4* wsb = (float4*)(ws + (size_t)bt * LSZ * 2);
    for (int i = tid; i < LSZ / 2; i += 512)
        wsb[i] = lds4[i];
}

// ---------------------------------------------------------------------------
// Phase B: gather for images [n0, n0+ni). Each output pixel sums the tile
// buffers whose halo'd window covers it (typically 4) plus the rare fallback
// contributions already atomically added into d_out. ws is read exactly once
// -> nontemporal loads keep it from thrashing L2/L3.
// ---------------------------------------------------------------------------
__global__ __launch_bounds__(256) void gather_kernel(
        const float* __restrict__ ws,
        float* __restrict__ out0,
        float* __restrict__ out1,
        int n0, int npix_chunk) {
    int lidx = blockIdx.x * blockDim.x + threadIdx.x;
    if (lidx >= npix_chunk) return;
    int w = lidx % W_;
    int t = lidx / W_;
    int h = t % H_;
    int nl = t / H_;                  // chunk-local image index

    int gidx = (n0 + nl) * HW + h * W_ + w;

    float fimg = out0[gidx];   // fallback accumulation (usually 0)
    float fone = out1[gidx];

    int tr_lo = (h >= R_) ? (h - R_) / TH : 0;
    int tr_hi = (h + R_) / TH; if (tr_hi > TILES_H - 1) tr_hi = TILES_H - 1;
    int tc_lo = (w >= R_) ? (w - R_) / TW : 0;
    int tc_hi = (w + R_) / TW; if (tc_hi > TILES_W - 1) tc_hi = TILES_W - 1;

    for (int tr = tr_lo; tr <= tr_hi; ++tr) {
        int lh = h - tr * TH + R_;
        for (int tc = tc_lo; tc <= tc_hi; ++tc) {
            int lw = w - tc * TW + R_;
            size_t base = ((size_t)((nl * TILES_H + tr) * TILES_W + tc)) * (LSZ * 2);
            const vfloat2* pp = (const vfloat2*)(ws + base + (size_t)(lh * LW + lw) * 2);
            vfloat2 v = __builtin_nontemporal_load(pp);
            fimg += v.x;
            fone += v.y;
        }
    }
    __builtin_nontemporal_store(fimg / (fone + EPS), &out0[gidx]);
    __builtin_nontemporal_store(fone, &out1[gidx]);
}

// ---------------------------------------------------------------------------
// Fallback path (ws smaller than one image's tiles): direct-atomic version.
// ---------------------------------------------------------------------------
__global__ void splat_atomic_kernel(const float* __restrict__ img,
                                    const float* __restrict__ counts,
                                    const float* __restrict__ flo,
                                    float* __restrict__ acc_img,
                                    float* __restrict__ acc_one) {
    int idx = blockIdx.x * blockDim.x + threadIdx.x;
    if (idx >= NPIX) return;
    int w = idx % W_;
    int t = idx / W_;
    int h = t % H_;
    int n = t / H_;

    float iv = img[idx];
    float cv = counts[idx];
    int fbase = ((n * 2) * H_ + h) * W_ + w;
    float y = flo[fbase];
    float x = flo[fbase + HW];

    float x1 = floorf(x);
    float y1 = floorf(y);
    float fx = x - x1, fy = y - y1;
    float gx = 1.0f - fx, gy = 1.0f - fy;
    float ex1 = __expf(-fx * fx), ex2 = __expf(-gx * gx);
    float ey1 = __expf(-fy * fy), ey2 = __expf(-gy * gy);
    float s = (ex1 + ex2) * (ey1 + ey2);
    float inv = cv / s;

    int ix1 = (int)x1 + h, ix2 = ix1 + 1;
    int iy1 = (int)y1 + w, iy2 = iy1 + 1;
    int nbase = n * HW;
    if ((unsigned)ix1 < (unsigned)H_ && (unsigned)iy1 < (unsigned)W_) {
        int o = nbase + ix1 * W_ + iy1; float ww = ex1 * ey1 * inv;
        fadd_native(acc_img + o, iv * ww); fadd_native(acc_one + o, ww);
    }
    if ((unsigned)ix1 < (unsigned)H_ && (unsigned)iy2 < (unsigned)W_) {
        int o = nbase + ix1 * W_ + iy2; float ww = ex1 * ey2 * inv;
        fadd_native(acc_img + o, iv * ww); fadd_native(acc_one + o, ww);
    }
    if ((unsigned)ix2 < (unsigned)H_ && (unsigned)iy1 < (unsigned)W_) {
        int o = nbase + ix2 * W_ + iy1; float ww = ex2 * ey1 * inv;
        fadd_native(acc_img + o, iv * ww); fadd_native(acc_one + o, ww);
    }
    if ((unsigned)ix2 < (unsigned)H_ && (unsigned)iy2 < (unsigned)W_) {
        int o = nbase + ix2 * W_ + iy2; float ww = ex2 * ey2 * inv;
        fadd_native(acc_img + o, iv * ww); fadd_native(acc_one + o, ww);
    }
}

__global__ void finalize_kernel(float* __restrict__ out0,
                                const float* __restrict__ out1) {
    int idx = blockIdx.x * blockDim.x + threadIdx.x;
    if (idx >= NPIX) return;
    out0[idx] = out0[idx] / (out1[idx] + EPS);
}

extern "C" void kernel_launch(void* const* d_in, const int* in_sizes, int n_in,
                              void* d_out, int out_size, void* d_ws, size_t ws_size,
                              hipStream_t stream) {
    const float* img    = (const float*)d_in[0];
    const float* counts = (const float*)d_in[1];
    const float* flo    = (const float*)d_in[2];

    float* out0 = (float*)d_out;
    float* out1 = out0 + NPIX;

    // d_out is re-poisoned before every call; both planes double as
    // fallback atomic accumulators -> zero them.
    (void)hipMemsetAsync(d_out, 0, (size_t)2 * NPIX * sizeof(float), stream);

    // images per chunk, limited by workspace (34 MiB per image of tiles)
    int ipc = (int)(ws_size / WS_PER_IMG);
    if (ipc > N_) ipc = N_;

    if (ipc >= 1) {
        float* ws = (float*)d_ws;  // one chunk region, reused (stream-serialized)
        for (int n0 = 0; n0 < N_; n0 += ipc) {
            int ni = (n0 + ipc <= N_) ? ipc : (N_ - n0);
            splat_tiled_kernel<<<ni * TILES_PER_IMG, 512, 0, stream>>>(
                img, counts, flo, ws, out0, out1, n0);
            int npix_chunk = ni * HW;
            gather_kernel<<<(npix_chunk + 255) / 256, 256, 0, stream>>>(
                ws, out0, out1, n0, npix_chunk);
        }
    } else {
        const int threads = 256;
        const int blocks = (NPIX + threads - 1) / threads;
        splat_atomic_kernel<<<blocks, threads, 0, stream>>>(img, counts, flo,
                                                            out0, out1);
        finalize_kernel<<<blocks, threads, 0, stream>>>(out0, out1);
    }
}